// Round 5
// baseline (597.221 us; speedup 1.0000x reference)
//
#include <hip/hip_runtime.h>
#include <hip/hip_bf16.h>

#define TT 1000
#define CC 3
#define HH 64
#define WW 64
#define HW 4096
#define CHW 12288
#define CHW4 3072            // CHW / 4
#define NCHUNK 500
#define CLEN 2               // NCHUNK*CLEN == TT

// out[0:CHW] = x[0:CHW] (d_out is re-poisoned before every call)
__global__ __launch_bounds__(256) void copy_xT_kernel(const float4* __restrict__ x,
                                                      float4* __restrict__ out) {
    int i = blockIdx.x * 256 + threadIdx.x;
    if (i < CHW4) out[i] = x[i];
}

// Pass 1: S[ch] = sum over the chunk's CLEN t's of et_updated[t]  (no A buffer).
// thread = (chunk, 2-row, 8-col); halos via wave shuffles (wi = lane&7).
__global__ __launch_bounds__(256) void conv_sum_kernel(const float* __restrict__ xin,
                                                       const float* __restrict__ cw,
                                                       const float* __restrict__ temb,
                                                       const int* __restrict__ tarr,
                                                       const float* __restrict__ ec,
                                                       float* __restrict__ S) {
    const int ch = blockIdx.x;          // block-uniform chunk id
    const int tid = threadIdx.x;
    const int wi = tid & 7;             // 8-col group, lane&7
    const int hp = tid >> 3;            // 0..31
    const int h0 = hp * 2;
    const int w0 = wi * 8;

    float sum[2][CC][8];
    #pragma unroll
    for (int o = 0; o < 2; ++o)
        #pragma unroll
        for (int co = 0; co < CC; ++co)
            #pragma unroll
            for (int k = 0; k < 8; ++k) sum[o][co][k] = 0.f;

    const float4 Z = make_float4(0.f, 0.f, 0.f, 0.f);
    #pragma unroll
    for (int i = 0; i < CLEN; ++i) {
        const int t = ch * CLEN + i;    // block-uniform
        const float* xt = xin + (size_t)t * CHW;
        const float e = ec[t];
        const int tr = tarr[t];
        #pragma unroll
        for (int co = 0; co < CC; ++co) {
            float eb = e * temb[tr * CC + co];
            #pragma unroll
            for (int o = 0; o < 2; ++o)
                #pragma unroll
                for (int k = 0; k < 8; ++k) sum[o][co][k] += eb;
        }
        #pragma unroll
        for (int ci = 0; ci < CC; ++ci) {
            const float* xc = xt + ci * HW;
            #pragma unroll
            for (int j = 0; j < 4; ++j) {       // input row h0-1+j
                int h = h0 - 1 + j;
                bool hv = (unsigned)h < (unsigned)HH;
                const float* row = xc + h * WW + w0;
                float4 M1 = hv ? *(const float4*)(row)     : Z;
                float4 M2 = hv ? *(const float4*)(row + 4) : Z;
                float left  = __shfl_up(M2.w, 1);   if (wi == 0) left  = 0.f;
                float right = __shfl_down(M1.x, 1); if (wi == 7) right = 0.f;
                // e-scaled window: et = sum w*(e*x) + e*bias
                float win[10] = {e * left, e * M1.x, e * M1.y, e * M1.z, e * M1.w,
                                 e * M2.x, e * M2.y, e * M2.z, e * M2.w, e * right};
                #pragma unroll
                for (int o = 0; o < 2; ++o) {
                    const int kh = j - o;
                    if (kh >= 0 && kh <= 2) {
                        #pragma unroll
                        for (int co = 0; co < CC; ++co) {
                            float wa = cw[((co * CC + ci) * 3 + kh) * 3 + 0];
                            float wb = cw[((co * CC + ci) * 3 + kh) * 3 + 1];
                            float wc = cw[((co * CC + ci) * 3 + kh) * 3 + 2];
                            #pragma unroll
                            for (int k = 0; k < 8; ++k)
                                sum[o][co][k] += win[k] * wa + win[k + 1] * wb + win[k + 2] * wc;
                        }
                    }
                }
            }
        }
    }

    #pragma unroll
    for (int o = 0; o < 2; ++o)
        #pragma unroll
        for (int co = 0; co < CC; ++co) {
            float* p = S + (size_t)ch * CHW + co * HW + (h0 + o) * WW + w0;
            *(float4*)(p)     = make_float4(sum[o][co][0], sum[o][co][1], sum[o][co][2], sum[o][co][3]);
            *(float4*)(p + 4) = make_float4(sum[o][co][4], sum[o][co][5], sum[o][co][6], sum[o][co][7]);
        }
}

// Pass 2: in-place exclusive scan of chunk totals, per float4 lane
__global__ __launch_bounds__(256) void offset_scan_kernel(float4* __restrict__ S) {
    int pos4 = blockIdx.x * 256 + threadIdx.x;
    if (pos4 >= CHW4) return;
    float4 run = make_float4(0.f, 0.f, 0.f, 0.f);
    for (int ch = 0; ch < NCHUNK; ++ch) {
        float4 v = S[(size_t)ch * CHW4 + pos4];
        S[(size_t)ch * CHW4 + pos4] = run;
        run.x += v.x; run.y += v.y; run.z += v.z; run.w += v.w;
    }
}

// Pass 3: recompute et, seed running sum with scanned prefix, write out directly.
__global__ __launch_bounds__(256) void conv_final_kernel(const float* __restrict__ xin,
                                                         const float* __restrict__ cw,
                                                         const float* __restrict__ temb,
                                                         const int* __restrict__ tarr,
                                                         const float* __restrict__ ec,
                                                         const float* __restrict__ S,
                                                         const float* __restrict__ xT,
                                                         const float* __restrict__ ar,
                                                         const float* __restrict__ epc,
                                                         float* __restrict__ out) {
    const int ch = blockIdx.x;
    const int tid = threadIdx.x;
    const int wi = tid & 7;
    const int hp = tid >> 3;
    const int h0 = hp * 2;
    const int w0 = wi * 8;

    float run[2][CC][8];
    float xv[2][CC][8];
    #pragma unroll
    for (int o = 0; o < 2; ++o)
        #pragma unroll
        for (int co = 0; co < CC; ++co) {
            const float* sp = S + (size_t)ch * CHW + co * HW + (h0 + o) * WW + w0;
            float4 a = *(const float4*)(sp);
            float4 b = *(const float4*)(sp + 4);
            run[o][co][0] = a.x; run[o][co][1] = a.y; run[o][co][2] = a.z; run[o][co][3] = a.w;
            run[o][co][4] = b.x; run[o][co][5] = b.y; run[o][co][6] = b.z; run[o][co][7] = b.w;
            const float* xp = xT + co * HW + (h0 + o) * WW + w0;
            float4 c = *(const float4*)(xp);
            float4 d = *(const float4*)(xp + 4);
            xv[o][co][0] = c.x; xv[o][co][1] = c.y; xv[o][co][2] = c.z; xv[o][co][3] = c.w;
            xv[o][co][4] = d.x; xv[o][co][5] = d.y; xv[o][co][6] = d.z; xv[o][co][7] = d.w;
        }

    const float4 Z = make_float4(0.f, 0.f, 0.f, 0.f);
    #pragma unroll
    for (int i = 0; i < CLEN; ++i) {
        const int t = ch * CLEN + i;    // block-uniform
        const float* xt = xin + (size_t)t * CHW;
        const float e = ec[t];
        const int tr = tarr[t];
        const float a_r = ar[t];
        const float ep = epc[t];
        #pragma unroll
        for (int co = 0; co < CC; ++co) {
            float eb = e * temb[tr * CC + co];
            #pragma unroll
            for (int o = 0; o < 2; ++o)
                #pragma unroll
                for (int k = 0; k < 8; ++k) run[o][co][k] += eb;
        }
        #pragma unroll
        for (int ci = 0; ci < CC; ++ci) {
            const float* xc = xt + ci * HW;
            #pragma unroll
            for (int j = 0; j < 4; ++j) {
                int h = h0 - 1 + j;
                bool hv = (unsigned)h < (unsigned)HH;
                const float* row = xc + h * WW + w0;
                float4 M1 = hv ? *(const float4*)(row)     : Z;
                float4 M2 = hv ? *(const float4*)(row + 4) : Z;
                float left  = __shfl_up(M2.w, 1);   if (wi == 0) left  = 0.f;
                float right = __shfl_down(M1.x, 1); if (wi == 7) right = 0.f;
                float win[10] = {e * left, e * M1.x, e * M1.y, e * M1.z, e * M1.w,
                                 e * M2.x, e * M2.y, e * M2.z, e * M2.w, e * right};
                #pragma unroll
                for (int o = 0; o < 2; ++o) {
                    const int kh = j - o;
                    if (kh >= 0 && kh <= 2) {
                        #pragma unroll
                        for (int co = 0; co < CC; ++co) {
                            float wa = cw[((co * CC + ci) * 3 + kh) * 3 + 0];
                            float wb = cw[((co * CC + ci) * 3 + kh) * 3 + 1];
                            float wc = cw[((co * CC + ci) * 3 + kh) * 3 + 2];
                            #pragma unroll
                            for (int k = 0; k < 8; ++k)
                                run[o][co][k] += win[k] * wa + win[k + 1] * wb + win[k + 2] * wc;
                        }
                    }
                }
            }
        }
        // out[t+1] = ar[t]*xT + epc[t]*run
        #pragma unroll
        for (int o = 0; o < 2; ++o)
            #pragma unroll
            for (int co = 0; co < CC; ++co) {
                float* q = out + (size_t)(t + 1) * CHW + co * HW + (h0 + o) * WW + w0;
                *(float4*)(q) = make_float4(a_r * xv[o][co][0] + ep * run[o][co][0],
                                            a_r * xv[o][co][1] + ep * run[o][co][1],
                                            a_r * xv[o][co][2] + ep * run[o][co][2],
                                            a_r * xv[o][co][3] + ep * run[o][co][3]);
                *(float4*)(q + 4) = make_float4(a_r * xv[o][co][4] + ep * run[o][co][4],
                                                a_r * xv[o][co][5] + ep * run[o][co][5],
                                                a_r * xv[o][co][6] + ep * run[o][co][6],
                                                a_r * xv[o][co][7] + ep * run[o][co][7]);
            }
    }
}

extern "C" void kernel_launch(void* const* d_in, const int* in_sizes, int n_in,
                              void* d_out, int out_size, void* d_ws, size_t ws_size,
                              hipStream_t stream) {
    const float* x    = (const float*)d_in[0];   // (T+1, C, H, W)
    const int*   tarr = (const int*)  d_in[1];   // (T,)
    const float* ar   = (const float*)d_in[2];   // (T,1,1,1)
    const float* ec   = (const float*)d_in[3];   // (T,1,1,1)
    const float* epc  = (const float*)d_in[4];   // (T,1,1,1)
    const float* cw   = (const float*)d_in[5];   // (C,C,3,3)
    const float* temb = (const float*)d_in[6];   // (T,C)
    float* out = (float*)d_out;                  // (T+1, C, H, W)

    float* S = (float*)d_ws;                     // NCHUNK*CHW floats (24.6 MB)

    copy_xT_kernel<<<12, 256, 0, stream>>>((const float4*)x, (float4*)out);

    for (int it = 0; it < 3; ++it) {
        const float* xin = (it == 0) ? x : out;  // slices 0..T-1 of previous xt
        conv_sum_kernel<<<NCHUNK, 256, 0, stream>>>(xin, cw, temb, tarr, ec, S);
        offset_scan_kernel<<<12, 256, 0, stream>>>((float4*)S);
        conv_final_kernel<<<NCHUNK, 256, 0, stream>>>(xin, cw, temb, tarr, ec, S,
                                                      x, ar, epc, out);
    }
}

// Round 6
// 227.081 us; speedup vs baseline: 2.6300x; 2.6300x over previous
//
#include <hip/hip_runtime.h>
#include <hip/hip_bf16.h>

#define TT 1000
#define CC 3
#define HH 64
#define WW 64
#define HW 4096
#define CHW 12288
#define CHW4 3072            // CHW / 4
#define NCHUNK 50
#define CLEN 20              // NCHUNK*CLEN == TT

// bf16 <-> f32 helpers (bf16 = top 16 bits of f32; RNE on encode)
__device__ __forceinline__ float bf2f(unsigned short u) {
    return __uint_as_float(((unsigned)u) << 16);
}
__device__ __forceinline__ unsigned short f2bf(float f) {
    unsigned u = __float_as_uint(f);
    return (unsigned short)((u + 0x7FFFu + ((u >> 16) & 1u)) >> 16);
}

// out[0:CHW] = x[0:CHW] (d_out is re-poisoned before every call)
__global__ __launch_bounds__(256) void copy_xT_kernel(const float4* __restrict__ x,
                                                      float4* __restrict__ out) {
    int i = blockIdx.x * 256 + threadIdx.x;
    if (i < CHW4) out[i] = x[i];
}

// A[t,c,h,w] = bf16( et_coeff[t] * (conv3x3(xin[t])[c,h,w] + temb[tarr[t], c]) )
// thread = (t, 2-row pair, 4-col group); 3 output channels share all loads.
// Halo columns via wave shuffles (wi = lane&15 -> +-1 lane is adjacent group).
__global__ __launch_bounds__(256) void conv_kernel(const float* __restrict__ xin,
                                                   const float* __restrict__ cw,
                                                   const float* __restrict__ temb,
                                                   const int* __restrict__ tarr,
                                                   const float* __restrict__ ec,
                                                   unsigned short* __restrict__ A) {
    int idx = blockIdx.x * 256 + threadIdx.x;   // TT*32*16 = 512000 exactly
    int wi = idx & 15;
    int hp = (idx >> 4) & 31;
    int t  = idx >> 9;                          // block-uniform (2 blocks/t)
    int h0 = hp * 2;
    int w0 = wi * 4;
    const float* xt = xin + (size_t)t * CHW;

    float acc[2][CC][4];
    #pragma unroll
    for (int o = 0; o < 2; ++o)
        #pragma unroll
        for (int co = 0; co < CC; ++co)
            #pragma unroll
            for (int k = 0; k < 4; ++k) acc[o][co][k] = 0.f;

    const float4 Z = make_float4(0.f, 0.f, 0.f, 0.f);
    #pragma unroll
    for (int ch = 0; ch < CC; ++ch) {
        const float* xc = xt + ch * HW;
        #pragma unroll
        for (int j = 0; j < 4; ++j) {           // input row h0-1+j
            int h = h0 - 1 + j;
            bool hv = (unsigned)h < (unsigned)HH;
            float4 M = hv ? *(const float4*)(xc + h * WW + w0) : Z;
            float left  = __shfl_up(M.w, 1);    if (wi == 0)  left  = 0.f;
            float right = __shfl_down(M.x, 1);  if (wi == 15) right = 0.f;
            float win[6] = {left, M.x, M.y, M.z, M.w, right};
            #pragma unroll
            for (int o = 0; o < 2; ++o) {
                const int kh = j - o;           // input row = (h0+o) + kh - 1
                if (kh >= 0 && kh <= 2) {
                    #pragma unroll
                    for (int co = 0; co < CC; ++co) {
                        float wa = cw[((co * CC + ch) * 3 + kh) * 3 + 0];
                        float wb = cw[((co * CC + ch) * 3 + kh) * 3 + 1];
                        float wc = cw[((co * CC + ch) * 3 + kh) * 3 + 2];
                        #pragma unroll
                        for (int k = 0; k < 4; ++k)
                            acc[o][co][k] += win[k] * wa + win[k + 1] * wb + win[k + 2] * wc;
                    }
                }
            }
        }
    }

    float e = ec[t];
    int tr = tarr[t];
    #pragma unroll
    for (int o = 0; o < 2; ++o)
        #pragma unroll
        for (int co = 0; co < CC; ++co) {
            float b = temb[tr * CC + co];
            ushort4 v;
            v.x = f2bf(e * (acc[o][co][0] + b));
            v.y = f2bf(e * (acc[o][co][1] + b));
            v.z = f2bf(e * (acc[o][co][2] + b));
            v.w = f2bf(e * (acc[o][co][3] + b));
            *(ushort4*)(A + (size_t)t * CHW + co * HW + (h0 + o) * WW + w0) = v;
        }
}

// S[ch,pos] = sum of A over the chunk's 20 t's (f32 accumulate from bf16)
__global__ __launch_bounds__(256) void chunk_sum_kernel(const unsigned short* __restrict__ A,
                                                        float4* __restrict__ S) {
    int ch = blockIdx.x / 12;                   // block-uniform
    int pos4 = (blockIdx.x % 12) * 256 + threadIdx.x;
    const unsigned short* p = A + (size_t)ch * CLEN * CHW + pos4 * 4;
    float4 acc = make_float4(0.f, 0.f, 0.f, 0.f);
    #pragma unroll
    for (int i = 0; i < CLEN; ++i) {
        ushort4 u = *(const ushort4*)(p + (size_t)i * CHW);
        acc.x += bf2f(u.x); acc.y += bf2f(u.y); acc.z += bf2f(u.z); acc.w += bf2f(u.w);
    }
    S[(size_t)ch * CHW4 + pos4] = acc;
}

// in-place exclusive scan of chunk totals, per float4 lane (f32)
__global__ __launch_bounds__(256) void offset_scan_kernel(float4* __restrict__ S) {
    int pos4 = blockIdx.x * 256 + threadIdx.x;
    if (pos4 >= CHW4) return;
    float4 run = make_float4(0.f, 0.f, 0.f, 0.f);
    #pragma unroll
    for (int ch = 0; ch < NCHUNK; ++ch) {
        float4 v = S[ch * CHW4 + pos4];
        S[ch * CHW4 + pos4] = run;
        run.x += v.x; run.y += v.y; run.z += v.z; run.w += v.w;
    }
}

// out[t+1] = ar[t]*xT + epc[t]*(chunk_offset + local running sum)  (f32 out)
__global__ __launch_bounds__(256) void final_kernel(const unsigned short* __restrict__ A,
                                                    const float4* __restrict__ S,
                                                    const float4* __restrict__ xT,
                                                    const float* __restrict__ ar,
                                                    const float* __restrict__ epc,
                                                    float4* __restrict__ out) {
    int ch = blockIdx.x / 12;                   // block-uniform
    int pos4 = (blockIdx.x % 12) * 256 + threadIdx.x;
    float4 acc = S[(size_t)ch * CHW4 + pos4];
    float4 xv = xT[pos4];
    const unsigned short* p = A + (size_t)ch * CLEN * CHW + pos4 * 4;
    float4* q = out + (size_t)(ch * CLEN + 1) * CHW4 + pos4;
    #pragma unroll
    for (int i = 0; i < CLEN; ++i) {
        int t = ch * CLEN + i;                  // block-uniform -> s_load
        ushort4 u = *(const ushort4*)(p + (size_t)i * CHW);
        acc.x += bf2f(u.x); acc.y += bf2f(u.y); acc.z += bf2f(u.z); acc.w += bf2f(u.w);
        float a = ar[t], e = epc[t];
        q[(size_t)i * CHW4] = make_float4(a * xv.x + e * acc.x, a * xv.y + e * acc.y,
                                          a * xv.z + e * acc.z, a * xv.w + e * acc.w);
    }
}

extern "C" void kernel_launch(void* const* d_in, const int* in_sizes, int n_in,
                              void* d_out, int out_size, void* d_ws, size_t ws_size,
                              hipStream_t stream) {
    const float* x    = (const float*)d_in[0];   // (T+1, C, H, W)
    const int*   tarr = (const int*)  d_in[1];   // (T,)
    const float* ar   = (const float*)d_in[2];   // (T,1,1,1)
    const float* ec   = (const float*)d_in[3];   // (T,1,1,1)
    const float* epc  = (const float*)d_in[4];   // (T,1,1,1)
    const float* cw   = (const float*)d_in[5];   // (C,C,3,3)
    const float* temb = (const float*)d_in[6];   // (T,C)
    float* out = (float*)d_out;                  // (T+1, C, H, W)

    unsigned short* A = (unsigned short*)d_ws;   // TT*CHW bf16 (24.6 MB)
    float* S = (float*)(A + (size_t)TT * CHW);   // NCHUNK*CHW f32 (2.46 MB)

    copy_xT_kernel<<<12, 256, 0, stream>>>((const float4*)x, (float4*)out);

    for (int it = 0; it < 3; ++it) {
        const float* xin = (it == 0) ? x : out;  // slices 0..T-1 of previous xt
        conv_kernel<<<2000, 256, 0, stream>>>(xin, cw, temb, tarr, ec, A);
        chunk_sum_kernel<<<NCHUNK * 12, 256, 0, stream>>>(A, (float4*)S);
        offset_scan_kernel<<<12, 256, 0, stream>>>((float4*)S);
        final_kernel<<<NCHUNK * 12, 256, 0, stream>>>(A, (const float4*)S,
                                                      (const float4*)x, ar, epc, (float4*)out);
    }
}

// Round 7
// 209.418 us; speedup vs baseline: 2.8518x; 1.0843x over previous
//
#include <hip/hip_runtime.h>
#include <hip/hip_bf16.h>

#define TT 1000
#define CC 3
#define HH 64
#define WW 64
#define HW 4096
#define CHW 12288
#define CHW4 3072            // CHW / 4
#define NCHUNK 50
#define CLEN 20              // NCHUNK*CLEN == TT

// bf16 <-> f32 helpers (bf16 = top 16 bits of f32; RNE on encode)
__device__ __forceinline__ float bf2f(unsigned short u) {
    return __uint_as_float(((unsigned)u) << 16);
}
__device__ __forceinline__ unsigned short f2bf(float f) {
    unsigned u = __float_as_uint(f);
    return (unsigned short)((u + 0x7FFFu + ((u >> 16) & 1u)) >> 16);
}

// out[0:CHW] = x[0:CHW] (f32) and X_ws[0:CHW] = bf16(x[0:CHW])
__global__ __launch_bounds__(256) void copy_xT_kernel(const float4* __restrict__ x,
                                                      float4* __restrict__ out,
                                                      unsigned short* __restrict__ X) {
    int i = blockIdx.x * 256 + threadIdx.x;
    if (i < CHW4) {
        float4 v = x[i];
        out[i] = v;
        ushort4 u;
        u.x = f2bf(v.x); u.y = f2bf(v.y); u.z = f2bf(v.z); u.w = f2bf(v.w);
        *(ushort4*)(X + i * 4) = u;
    }
}

// A[t,c,h,w] = bf16( et_coeff[t] * (conv3x3(xin[t])[c,h,w] + temb[tarr[t], c]) )
// thread = (t, 2-row pair, 4-col group); 3 output channels share all loads.
// Halo columns via wave shuffles. Input either f32 (iter 1) or bf16 state.
template <bool IN_BF16>
__global__ __launch_bounds__(256) void conv_kernel(const void* __restrict__ xin_v,
                                                   const float* __restrict__ cw,
                                                   const float* __restrict__ temb,
                                                   const int* __restrict__ tarr,
                                                   const float* __restrict__ ec,
                                                   unsigned short* __restrict__ A) {
    int idx = blockIdx.x * 256 + threadIdx.x;   // TT*32*16 = 512000 exactly
    int wi = idx & 15;
    int hp = (idx >> 4) & 31;
    int t  = idx >> 9;                          // block-uniform (2 blocks/t)
    int h0 = hp * 2;
    int w0 = wi * 4;

    const float* xtf = (const float*)xin_v + (size_t)t * CHW;
    const unsigned short* xtb = (const unsigned short*)xin_v + (size_t)t * CHW;

    float acc[2][CC][4];
    #pragma unroll
    for (int o = 0; o < 2; ++o)
        #pragma unroll
        for (int co = 0; co < CC; ++co)
            #pragma unroll
            for (int k = 0; k < 4; ++k) acc[o][co][k] = 0.f;

    #pragma unroll
    for (int ch = 0; ch < CC; ++ch) {
        #pragma unroll
        for (int j = 0; j < 4; ++j) {           // input row h0-1+j
            int h = h0 - 1 + j;
            bool hv = (unsigned)h < (unsigned)HH;
            float4 M;
            if (IN_BF16) {
                ushort4 u = make_ushort4(0, 0, 0, 0);
                if (hv) u = *(const ushort4*)(xtb + ch * HW + h * WW + w0);
                M = make_float4(bf2f(u.x), bf2f(u.y), bf2f(u.z), bf2f(u.w));
            } else {
                M = hv ? *(const float4*)(xtf + ch * HW + h * WW + w0)
                       : make_float4(0.f, 0.f, 0.f, 0.f);
            }
            float left  = __shfl_up(M.w, 1);    if (wi == 0)  left  = 0.f;
            float right = __shfl_down(M.x, 1);  if (wi == 15) right = 0.f;
            float win[6] = {left, M.x, M.y, M.z, M.w, right};
            #pragma unroll
            for (int o = 0; o < 2; ++o) {
                const int kh = j - o;           // input row = (h0+o) + kh - 1
                if (kh >= 0 && kh <= 2) {
                    #pragma unroll
                    for (int co = 0; co < CC; ++co) {
                        float wa = cw[((co * CC + ch) * 3 + kh) * 3 + 0];
                        float wb = cw[((co * CC + ch) * 3 + kh) * 3 + 1];
                        float wc = cw[((co * CC + ch) * 3 + kh) * 3 + 2];
                        #pragma unroll
                        for (int k = 0; k < 4; ++k)
                            acc[o][co][k] += win[k] * wa + win[k + 1] * wb + win[k + 2] * wc;
                    }
                }
            }
        }
    }

    float e = ec[t];
    int tr = tarr[t];
    #pragma unroll
    for (int o = 0; o < 2; ++o)
        #pragma unroll
        for (int co = 0; co < CC; ++co) {
            float b = temb[tr * CC + co];
            ushort4 v;
            v.x = f2bf(e * (acc[o][co][0] + b));
            v.y = f2bf(e * (acc[o][co][1] + b));
            v.z = f2bf(e * (acc[o][co][2] + b));
            v.w = f2bf(e * (acc[o][co][3] + b));
            *(ushort4*)(A + (size_t)t * CHW + co * HW + (h0 + o) * WW + w0) = v;
        }
}

// S[ch,pos] = sum of A over the chunk's 20 t's (f32 accumulate from bf16)
__global__ __launch_bounds__(256) void chunk_sum_kernel(const unsigned short* __restrict__ A,
                                                        float4* __restrict__ S) {
    int ch = blockIdx.x / 12;                   // block-uniform
    int pos4 = (blockIdx.x % 12) * 256 + threadIdx.x;
    const unsigned short* p = A + (size_t)ch * CLEN * CHW + pos4 * 4;
    float4 acc = make_float4(0.f, 0.f, 0.f, 0.f);
    #pragma unroll
    for (int i = 0; i < CLEN; ++i) {
        ushort4 u = *(const ushort4*)(p + (size_t)i * CHW);
        acc.x += bf2f(u.x); acc.y += bf2f(u.y); acc.z += bf2f(u.z); acc.w += bf2f(u.w);
    }
    S[(size_t)ch * CHW4 + pos4] = acc;
}

// in-place exclusive scan of chunk totals, per float4 lane (f32)
__global__ __launch_bounds__(256) void offset_scan_kernel(float4* __restrict__ S) {
    int pos4 = blockIdx.x * 256 + threadIdx.x;
    if (pos4 >= CHW4) return;
    float4 run = make_float4(0.f, 0.f, 0.f, 0.f);
    #pragma unroll
    for (int ch = 0; ch < NCHUNK; ++ch) {
        float4 v = S[ch * CHW4 + pos4];
        S[ch * CHW4 + pos4] = run;
        run.x += v.x; run.y += v.y; run.z += v.z; run.w += v.w;
    }
}

// xt_next[t] = ar[t]*xT + epc[t]*(chunk_offset + local running sum)
// OUT_BF16: write bf16 state X_ws[t+1] (iters 1,2). Else f32 d_out[t+1] (iter 3).
template <bool OUT_BF16>
__global__ __launch_bounds__(256) void final_kernel(const unsigned short* __restrict__ A,
                                                    const float4* __restrict__ S,
                                                    const float4* __restrict__ xT,
                                                    const float* __restrict__ ar,
                                                    const float* __restrict__ epc,
                                                    void* __restrict__ out_v) {
    int ch = blockIdx.x / 12;                   // block-uniform
    int pos4 = (blockIdx.x % 12) * 256 + threadIdx.x;
    float4 acc = S[(size_t)ch * CHW4 + pos4];
    float4 xv = xT[pos4];
    const unsigned short* p = A + (size_t)ch * CLEN * CHW + pos4 * 4;
    float4* qf = (float4*)out_v + (size_t)(ch * CLEN + 1) * CHW4 + pos4;
    unsigned short* qb = (unsigned short*)out_v + ((size_t)(ch * CLEN + 1) * CHW4 + pos4) * 4;
    #pragma unroll
    for (int i = 0; i < CLEN; ++i) {
        int t = ch * CLEN + i;                  // block-uniform -> s_load
        ushort4 u = *(const ushort4*)(p + (size_t)i * CHW);
        acc.x += bf2f(u.x); acc.y += bf2f(u.y); acc.z += bf2f(u.z); acc.w += bf2f(u.w);
        float a = ar[t], e = epc[t];
        float4 r = make_float4(a * xv.x + e * acc.x, a * xv.y + e * acc.y,
                               a * xv.z + e * acc.z, a * xv.w + e * acc.w);
        if (OUT_BF16) {
            ushort4 ub;
            ub.x = f2bf(r.x); ub.y = f2bf(r.y); ub.z = f2bf(r.z); ub.w = f2bf(r.w);
            *(ushort4*)(qb + (size_t)i * CHW) = ub;
        } else {
            qf[(size_t)i * CHW4] = r;
        }
    }
}

extern "C" void kernel_launch(void* const* d_in, const int* in_sizes, int n_in,
                              void* d_out, int out_size, void* d_ws, size_t ws_size,
                              hipStream_t stream) {
    const float* x    = (const float*)d_in[0];   // (T+1, C, H, W)
    const int*   tarr = (const int*)  d_in[1];   // (T,)
    const float* ar   = (const float*)d_in[2];   // (T,1,1,1)
    const float* ec   = (const float*)d_in[3];   // (T,1,1,1)
    const float* epc  = (const float*)d_in[4];   // (T,1,1,1)
    const float* cw   = (const float*)d_in[5];   // (C,C,3,3)
    const float* temb = (const float*)d_in[6];   // (T,C)
    float* out = (float*)d_out;                  // (T+1, C, H, W)

    unsigned short* A = (unsigned short*)d_ws;      // TT*CHW bf16 (24.6 MB)
    float* S = (float*)(A + (size_t)TT * CHW);      // NCHUNK*CHW f32 (2.46 MB)
    unsigned short* X = (unsigned short*)(S + (size_t)NCHUNK * CHW);  // (TT+1)*CHW bf16 state

    // out[0] = xT (f32), X[0] = bf16(xT)
    copy_xT_kernel<<<12, 256, 0, stream>>>((const float4*)x, (float4*)out, X);

    // iter 1: f32 x in -> bf16 X state out
    conv_kernel<false><<<2000, 256, 0, stream>>>(x, cw, temb, tarr, ec, A);
    chunk_sum_kernel<<<NCHUNK * 12, 256, 0, stream>>>(A, (float4*)S);
    offset_scan_kernel<<<12, 256, 0, stream>>>((float4*)S);
    final_kernel<true><<<NCHUNK * 12, 256, 0, stream>>>(A, (const float4*)S,
                                                        (const float4*)x, ar, epc, X);

    // iter 2: bf16 X in -> bf16 X out
    conv_kernel<true><<<2000, 256, 0, stream>>>(X, cw, temb, tarr, ec, A);
    chunk_sum_kernel<<<NCHUNK * 12, 256, 0, stream>>>(A, (float4*)S);
    offset_scan_kernel<<<12, 256, 0, stream>>>((float4*)S);
    final_kernel<true><<<NCHUNK * 12, 256, 0, stream>>>(A, (const float4*)S,
                                                        (const float4*)x, ar, epc, X);

    // iter 3: bf16 X in -> f32 d_out
    conv_kernel<true><<<2000, 256, 0, stream>>>(X, cw, temb, tarr, ec, A);
    chunk_sum_kernel<<<NCHUNK * 12, 256, 0, stream>>>(A, (float4*)S);
    offset_scan_kernel<<<12, 256, 0, stream>>>((float4*)S);
    final_kernel<false><<<NCHUNK * 12, 256, 0, stream>>>(A, (const float4*)S,
                                                         (const float4*)x, ar, epc, out);
}